// Round 4
// baseline (275.018 us; speedup 1.0000x reference)
//
#include <hip/hip_runtime.h>
#include <hip/hip_bf16.h>
#include <stdint.h>

// BasePairingAttention: B=8, S=T=1024, E=512, H=8, D=64
// Pipeline (5 kernels):
//  1) k_convert_w  : Wq/Wk/Wv/Wo fp32 -> transposed bf16 (WT[n][k], WoT)
//  2) k_gemm_qkv   : Y[8192][1536] = [q|k|v] @ W^T + bias (bf16); A converted
//                    fp32->bf16 in reg-staging, B via global_load_lds
//  3) k_transpose_v: vT[(b*8+h)*64+d][s] bf16
//  4) k_attention  : 2-pass, zero score storage. Pass1: QK MFMA -> row sums
//                    (fixed softmax shift M=12) + packed bonus/mask bits.
//                    Pass2: recompute QK, write probs from regs, PV MFMA.
//                    K/V read direct from global (L2-resident), ~11KB LDS,
//                    low VGPR -> 4+ blocks/CU.
//  5) k_gemm_o     : out = AO @ Wo + bo (fp32)

typedef float  f32x4  __attribute__((ext_vector_type(4)));
typedef short  s16x8  __attribute__((ext_vector_type(8)));

__device__ __forceinline__ ushort f2bf(float f) {
  union { float f; uint32_t u; } v; v.f = f;
  uint32_t u = v.u;
  return (ushort)((u + 0x7FFF + ((u >> 16) & 1)) >> 16);   // RNE
}

__device__ __forceinline__ f32x4 mfma16(s16x8 a, s16x8 b, f32x4 c) {
  return __builtin_amdgcn_mfma_f32_16x16x32_bf16(a, b, c, 0, 0, 0);
}

// async global->LDS, 16B per lane; LDS dest wave-uniform base + lane*16
__device__ __forceinline__ void gl_lds16(const void* g, void* l) {
  typedef __attribute__((address_space(1))) const void gvoid;
  typedef __attribute__((address_space(3))) void lvoid;
  __builtin_amdgcn_global_load_lds((gvoid*)(uintptr_t)g,
                                   (lvoid*)(uint32_t)(uintptr_t)l, 16, 0, 0);
}

// ---------------------------------------------------------------- convert W
__global__ __launch_bounds__(256) void k_convert_w(
    const float* __restrict__ Wq, const float* __restrict__ Wk,
    const float* __restrict__ Wv, const float* __restrict__ Wo,
    ushort* __restrict__ WT, ushort* __restrict__ WoT) {
  int idx = blockIdx.x * 256 + threadIdx.x;  // 2048*512 total
  int row = idx >> 9;
  int k = idx & 511;
  if (row < 1536) {
    const float* W = (row < 512) ? Wq : (row < 1024 ? Wk : Wv);
    int n = row & 511;
    WT[row * 512 + k] = f2bf(W[k * 512 + n]);
  } else {
    int n = row - 1536;
    WoT[n * 512 + k] = f2bf(Wo[k * 512 + n]);
  }
}

// ---------------------------------------------------------------- QKV GEMM
// 128x128 tile, BK=64, 4 waves each 64x64. A: fp32 global -> reg cvt ->
// swizzled LDS (fused convert). B: global_load_lds pre-swizzled source.
__global__ __launch_bounds__(256) void k_gemm_qkv(
    const float* __restrict__ Aq, const float* __restrict__ Ak,
    const float* __restrict__ Av, const ushort* __restrict__ WT,
    const float* __restrict__ bq, const float* __restrict__ bk,
    const float* __restrict__ bv, ushort* __restrict__ Y) {
  __shared__ ushort As[128 * 64];
  __shared__ ushort Bs[128 * 64];
  const int id = blockIdx.x;                // 768
  const int xcd = id & 7, slot = id >> 3;   // slot 0..95
  const int mb = xcd * 8 + slot / 12;       // A-panel L2-local per XCD
  const int nb = slot % 12;
  const int mat = nb >> 2;
  const float* A    = (mat == 0) ? Aq : (mat == 1 ? Ak : Av);
  const float* bias = (mat == 0) ? bq : (mat == 1 ? bk : bv);
  const int tid = threadIdx.x;
  const int w = tid >> 6, l = tid & 63;
  const int wr = (w >> 1) * 64, wc = (w & 1) * 64;
  const int lr = l & 15, lg = l >> 4;
  const int srow = l >> 3, sslot = (l & 7) ^ srow;

  f32x4 acc[4][4];
#pragma unroll
  for (int i = 0; i < 4; i++)
#pragma unroll
    for (int j = 0; j < 4; j++) acc[i][j] = (f32x4){0.f, 0.f, 0.f, 0.f};

  for (int kk = 0; kk < 8; kk++) {
    const int k0 = kk * 64;
    // stage A (fused fp32->bf16)
#pragma unroll
    for (int it = 0; it < 8; it++) {
      int s2 = it * 256 + tid;             // 2048 float4 slots
      int row = s2 >> 4;
      int k4 = (s2 & 15) * 4;
      float4 v = *reinterpret_cast<const float4*>(
          &A[(size_t)(mb * 128 + row) * 512 + k0 + k4]);
      uint64_t p = (uint64_t)f2bf(v.x) | ((uint64_t)f2bf(v.y) << 16) |
                   ((uint64_t)f2bf(v.z) << 32) | ((uint64_t)f2bf(v.w) << 48);
      int boff = row * 128 + ((k4 * 2) ^ ((row & 7) << 4));
      *reinterpret_cast<uint64_t*>((char*)As + boff) = p;
    }
    // stage B via async LDS
#pragma unroll
    for (int it = 0; it < 4; it++) {
      int g8 = it * 4 + w;
      int row = g8 * 8 + srow;
      gl_lds16(&WT[(size_t)(nb * 128 + row) * 512 + k0 + sslot * 8], &Bs[g8 * 512]);
    }
    __syncthreads();
#pragma unroll
    for (int ks = 0; ks < 2; ks++) {
      s16x8 af[4], bfr[4];
#pragma unroll
      for (int mt = 0; mt < 4; mt++) {
        int row = wr + mt * 16 + lr;
        af[mt] = *reinterpret_cast<const s16x8*>(
            (char*)As + row * 128 + ((ks * 64 + lg * 16) ^ ((row & 7) << 4)));
      }
#pragma unroll
      for (int nt = 0; nt < 4; nt++) {
        int row = wc + nt * 16 + lr;
        bfr[nt] = *reinterpret_cast<const s16x8*>(
            (char*)Bs + row * 128 + ((ks * 64 + lg * 16) ^ ((row & 7) << 4)));
      }
#pragma unroll
      for (int mt = 0; mt < 4; mt++)
#pragma unroll
        for (int nt = 0; nt < 4; nt++)
          acc[mt][nt] = mfma16(af[mt], bfr[nt], acc[mt][nt]);
    }
    __syncthreads();
  }
  const int ncb = nb * 128;
#pragma unroll
  for (int nt = 0; nt < 4; nt++) {
    int gcol = ncb + wc + nt * 16 + lr;
    float bv_ = bias[gcol & 511];
#pragma unroll
    for (int mt = 0; mt < 4; mt++) {
#pragma unroll
      for (int r = 0; r < 4; r++) {
        int grow = mb * 128 + wr + mt * 16 + lg * 4 + r;
        Y[(size_t)grow * 1536 + gcol] = f2bf(acc[mt][nt][r] + bv_);
      }
    }
  }
}

// ---------------------------------------------------------------- V transpose
__global__ __launch_bounds__(256) void k_transpose_v(
    const ushort* __restrict__ Y, ushort* __restrict__ vT) {
  __shared__ ushort T[64 * 64];
  const int sc = blockIdx.x;  // 16
  const int bh = blockIdx.y;  // 64
  const int b = bh >> 3, h = bh & 7;
  const int s0 = sc * 64;
  const int tid = threadIdx.x;
#pragma unroll
  for (int it = 0; it < 2; it++) {
    int slot = it * 256 + tid;
    int srw = slot >> 3;
    int i16 = (slot & 7) * 16;
    int4 v = *reinterpret_cast<const int4*>(
        &Y[(size_t)(b * 1024 + s0 + srw) * 1536 + 1024 + h * 64 + (slot & 7) * 8]);
    *reinterpret_cast<int4*>((char*)T + srw * 128 + (i16 ^ ((srw & 7) << 4))) = v;
  }
  __syncthreads();
  const int d = tid >> 2;
  const int sseg = (tid & 3) * 16;
  int pk[8];
#pragma unroll
  for (int j = 0; j < 8; j++) {
    int s0l = sseg + 2 * j;
    uint32_t a = *reinterpret_cast<const ushort*>(
        (char*)T + s0l * 128 + ((d * 2) ^ ((s0l & 7) << 4)));
    uint32_t bb = *reinterpret_cast<const ushort*>(
        (char*)T + (s0l + 1) * 128 + ((d * 2) ^ (((s0l + 1) & 7) << 4)));
    pk[j] = (int)(a | (bb << 16));
  }
  ushort* dst = &vT[(size_t)(bh * 64 + d) * 1024 + s0 + sseg];
  int4 o0 = {pk[0], pk[1], pk[2], pk[3]};
  int4 o1 = {pk[4], pk[5], pk[6], pk[7]};
  *reinterpret_cast<int4*>(dst) = o0;
  *reinterpret_cast<int4*>(dst + 8) = o1;
}

// ---------------------------------------------------------------- attention
// Block = (b,h,16 t-rows), 4 waves, each owning 16 s-cols (pass QK) / 16
// d-cols (PV). Two QK passes, zero score storage, fixed shift M=12.
__global__ __launch_bounds__(256, 4) void k_attention(
    const ushort* __restrict__ Y, const ushort* __restrict__ vT,
    const int* __restrict__ seq, const unsigned char* __restrict__ mask,
    float* __restrict__ probs, ushort* __restrict__ AO) {
  __shared__ int seqm[1024];
  __shared__ ushort Pb[16 * 72];    // bf16 P bounce, row stride 144B
  __shared__ float Rbuf[1024];      // (w,lg,r) x lr  -- FIX: was 256 (OOB)
  __shared__ float rinv_s[16];

  const int id = blockIdx.x;              // 4096
  const int xcd = id & 7, slot = id >> 3; // 512
  const int bh = xcd * 8 + (slot >> 6);   // K/V L2-resident per XCD
  const int tb = slot & 63;
  const int b = bh >> 3, h = bh & 7;
  const int tid = threadIdx.x;
  const int w = tid >> 6, l = tid & 63;
  const int lr = l & 15, lg = l >> 4;
  const int sc_ = w * 16;

#pragma unroll
  for (int it = 0; it < 4; it++) {
    int s = it * 256 + tid;
    seqm[s] = seq[b * 1024 + s] | (mask[b * 1024 + s] ? 0x100 : 0);
  }
  const ushort* qp = &Y[(size_t)(b * 1024 + tb * 16 + lr) * 1536 + h * 64 + lg * 8];
  s16x8 qf0 = *reinterpret_cast<const s16x8*>(qp);
  s16x8 qf1 = *reinterpret_cast<const s16x8*>(qp + 32);
  __syncthreads();

  int seqt[4];
#pragma unroll
  for (int r = 0; r < 4; r++) seqt[r] = seqm[tb * 16 + lg * 4 + r] & 255;

  const ushort* kbase = &Y[(size_t)(b * 1024) * 1536 + 512 + h * 64];
  const int srw = sc_ + lr;  // lane's s-col within each 64-chunk

  // ---- pass 1: row sums + packed bonus/mask bits
  uint32_t bb0 = 0, bb1 = 0, mk = 0;
  float psum[4] = {0.f, 0.f, 0.f, 0.f};
#pragma unroll
  for (int c = 0; c < 16; c++) {
    const int sg = c * 64 + srw;
    const ushort* kp = kbase + (size_t)sg * 1536;
    s16x8 kf0 = *reinterpret_cast<const s16x8*>(kp + lg * 8);
    s16x8 kf1 = *reinterpret_cast<const s16x8*>(kp + 32 + lg * 8);
    f32x4 facc = (f32x4){0.f, 0.f, 0.f, 0.f};
    facc = mfma16(qf0, kf0, facc);
    facc = mfma16(qf1, kf1, facc);
    const int sm = seqm[sg];
    const int ss = sm & 255;
    const bool msk = (sm & 0x100) != 0;
    uint32_t bits = 0;
#pragma unroll
    for (int r = 0; r < 4; r++) {
      int tg = tb * 16 + lg * 4 + r;
      int dsep = tg - sg; dsep = dsep < 0 ? -dsep : dsep;
      int dnt = seqt[r] - ss; dnt = dnt < 0 ? -dnt : dnt;
      bool bon = (dnt == 1 && seqt[r] <= 3 && ss <= 3 && dsep >= 3);
      float v = facc[r] * 0.125f + (bon ? 2.0f : 0.0f);
      float ee = msk ? 0.0f : __expf(v - 12.0f);
      psum[r] += ee;
      bits |= (bon ? 1u : 0u) << r;
    }
    if (c < 8) bb0 |= bits << (4 * c); else bb1 |= bits << (4 * (c - 8));
    mk |= (msk ? 1u : 0u) << c;
  }

  // ---- row-sum reduce across waves/lanes
#pragma unroll
  for (int r = 0; r < 4; r++) Rbuf[((w * 4 + lg) * 4 + r) * 16 + lr] = psum[r];
  __syncthreads();
  {
    int row = tid >> 4, j = tid & 15;
    int lgr = row >> 2, rr = row & 3;
    float s = 0.f;
#pragma unroll
    for (int i = 0; i < 4; i++) {
      int wj = j >> 2;
      int lrj = (j & 3) * 4 + i;
      s += Rbuf[((wj * 4 + lgr) * 4 + rr) * 16 + lrj];
    }
#pragma unroll
    for (int off = 1; off < 16; off <<= 1) s += __shfl_xor(s, off);
    if (j == 0) rinv_s[row] = 1.0f / s;
  }
  __syncthreads();
  float rv[4];
#pragma unroll
  for (int r = 0; r < 4; r++) rv[r] = rinv_s[lg * 4 + r];

  // ---- pass 2: recompute scores, write probs, PV
  f32x4 oacc = (f32x4){0.f, 0.f, 0.f, 0.f};
  const ushort* vbase = &vT[(size_t)(bh * 64) * 1024];
#pragma unroll
  for (int c = 0; c < 16; c++) {
    const int sg = c * 64 + srw;
    const ushort* kp = kbase + (size_t)sg * 1536;
    s16x8 kf0 = *reinterpret_cast<const s16x8*>(kp + lg * 8);
    s16x8 kf1 = *reinterpret_cast<const s16x8*>(kp + 32 + lg * 8);
    f32x4 facc = (f32x4){0.f, 0.f, 0.f, 0.f};
    facc = mfma16(qf0, kf0, facc);
    facc = mfma16(qf1, kf1, facc);
    const uint32_t bits = ((c < 8) ? (bb0 >> (4 * c)) : (bb1 >> (4 * (c - 8)))) & 15u;
    const bool msk = (mk >> c) & 1u;
#pragma unroll
    for (int r = 0; r < 4; r++) {
      float v = facc[r] * 0.125f + (((bits >> r) & 1u) ? 2.0f : 0.0f);
      float ee = msk ? 0.0f : __expf(v - 12.0f);
      probs[((size_t)bh * 1024 + tb * 16 + lg * 4 + r) * 1024 + c * 64 + srw] =
          ee * rv[r];
      Pb[(lg * 4 + r) * 72 + srw] = f2bf(ee);
    }
    __syncthreads();   // Pb visible to all waves
#pragma unroll
    for (int ks = 0; ks < 2; ks++) {
      s16x8 paf = *reinterpret_cast<const s16x8*>(&Pb[lr * 72 + ks * 32 + lg * 8]);
      s16x8 vb = *reinterpret_cast<const s16x8*>(
          &vbase[(size_t)(sc_ + lr) * 1024 + c * 64 + ks * 32 + lg * 8]);
      oacc = mfma16(paf, vb, oacc);
    }
    __syncthreads();   // Pb reads done before next publish
  }
  // AO write (normalized)
#pragma unroll
  for (int r = 0; r < 4; r++) {
    int t = tb * 16 + lg * 4 + r;
    AO[((size_t)b * 1024 + t) * 512 + h * 64 + sc_ + lr] = f2bf(oacc[r] * rv[r]);
  }
}

// ---------------------------------------------------------------- out GEMM
__global__ __launch_bounds__(256) void k_gemm_o(
    const ushort* __restrict__ AO, const ushort* __restrict__ WoT,
    const float* __restrict__ bo, float* __restrict__ out) {
  __shared__ ushort As[128 * 64];
  __shared__ ushort Bs[128 * 64];
  const int id = blockIdx.x;               // 256
  const int xcd = id & 7, slot = id >> 3;  // 0..31
  const int mb = xcd * 8 + (slot >> 2);
  const int nb = slot & 3;
  const int tid = threadIdx.x;
  const int w = tid >> 6, l = tid & 63;
  const int wr = (w >> 1) * 64, wc = (w & 1) * 64;
  const int lr = l & 15, lg = l >> 4;
  const int srow = l >> 3, sslot = (l & 7) ^ srow;

  f32x4 acc[4][4];
#pragma unroll
  for (int i = 0; i < 4; i++)
#pragma unroll
    for (int j = 0; j < 4; j++) acc[i][j] = (f32x4){0.f, 0.f, 0.f, 0.f};

  for (int kk = 0; kk < 8; kk++) {
    const int k0 = kk * 64;
#pragma unroll
    for (int it = 0; it < 4; it++) {
      int g8 = it * 4 + w;
      int row = g8 * 8 + srow;
      gl_lds16(&AO[(size_t)(mb * 128 + row) * 512 + k0 + sslot * 8], &As[g8 * 512]);
      gl_lds16(&WoT[(size_t)(nb * 128 + row) * 512 + k0 + sslot * 8], &Bs[g8 * 512]);
    }
    __syncthreads();
#pragma unroll
    for (int ks = 0; ks < 2; ks++) {
      s16x8 af[4], bfr[4];
#pragma unroll
      for (int mt = 0; mt < 4; mt++) {
        int row = wr + mt * 16 + lr;
        af[mt] = *reinterpret_cast<const s16x8*>(
            (char*)As + row * 128 + ((ks * 64 + lg * 16) ^ ((row & 7) << 4)));
      }
#pragma unroll
      for (int nt = 0; nt < 4; nt++) {
        int row = wc + nt * 16 + lr;
        bfr[nt] = *reinterpret_cast<const s16x8*>(
            (char*)Bs + row * 128 + ((ks * 64 + lg * 16) ^ ((row & 7) << 4)));
      }
#pragma unroll
      for (int mt = 0; mt < 4; mt++)
#pragma unroll
        for (int nt = 0; nt < 4; nt++)
          acc[mt][nt] = mfma16(af[mt], bfr[nt], acc[mt][nt]);
    }
    __syncthreads();
  }
  const int ncb = nb * 128;
#pragma unroll
  for (int nt = 0; nt < 4; nt++) {
    int gcol = ncb + wc + nt * 16 + lr;
    float bv_ = bo[gcol];
#pragma unroll
    for (int mt = 0; mt < 4; mt++) {
#pragma unroll
      for (int r = 0; r < 4; r++) {
        int grow = mb * 128 + wr + mt * 16 + lg * 4 + r;
        out[(size_t)grow * 512 + gcol] = acc[mt][nt][r] + bv_;
      }
    }
  }
}

// ---------------------------------------------------------------- launch
extern "C" void kernel_launch(void* const* d_in, const int* in_sizes, int n_in,
                              void* d_out, int out_size, void* d_ws, size_t ws_size,
                              hipStream_t stream) {
  (void)in_sizes; (void)n_in; (void)out_size; (void)ws_size;
  const float* query = (const float*)d_in[0];
  const float* key   = (const float*)d_in[1];
  const float* value = (const float*)d_in[2];
  const int* seq     = (const int*)d_in[3];
  const unsigned char* mask = (const unsigned char*)d_in[4];
  const float* Wq = (const float*)d_in[5];
  const float* bq = (const float*)d_in[6];
  const float* Wk = (const float*)d_in[7];
  const float* bk = (const float*)d_in[8];
  const float* Wv = (const float*)d_in[9];
  const float* bv = (const float*)d_in[10];
  const float* Wo = (const float*)d_in[11];
  const float* bo = (const float*)d_in[12];

  float* out = (float*)d_out;
  float* probs = out + (size_t)8 * 1024 * 512;

  char* ws = (char*)d_ws;
  ushort* Y   = (ushort*)(ws);               // 25,165,824 B
  ushort* WT  = (ushort*)(ws + 25165824);    // 1,572,864 B
  ushort* WoT = (ushort*)(ws + 26738688);    //   524,288 B
  ushort* vT  = (ushort*)(ws + 27262976);    // 8,388,608 B
  ushort* AO  = (ushort*)(ws + 35651584);    // 8,388,608 B (total 44,040,192)

  k_convert_w<<<4096, 256, 0, stream>>>(Wq, Wk, Wv, Wo, WT, WoT);
  k_gemm_qkv<<<768, 256, 0, stream>>>(query, key, value, WT, bq, bk, bv, Y);
  k_transpose_v<<<dim3(16, 64), 256, 0, stream>>>(Y, vT);
  k_attention<<<4096, 256, 0, stream>>>(Y, vT, seq, mask, probs, AO);
  k_gemm_o<<<256, 256, 0, stream>>>(AO, WoT, bo, out);
}

// Round 5
// 219.584 us; speedup vs baseline: 1.2525x; 1.2525x over previous
//
#include <hip/hip_runtime.h>
#include <hip/hip_bf16.h>
#include <stdint.h>

// BasePairingAttention: B=8, S=T=1024, E=512, H=8, D=64
// Pipeline (5 kernels):
//  1) k_convert_w  : Wq/Wk/Wv/Wo fp32 -> transposed bf16 (WT[n][k], WoT)
//  2) k_gemm_qkv   : Y[8192][1536] = [q|k|v] @ W^T + bias (bf16)
//  3) k_transpose_v: vT[(b*8+h)*64+d][s] bf16
//  4) k_attention  : single QK+PV pass, ALL K/V/Q through coalesced
//                    global_load_lds staging (no per-lane gathers), e kept
//                    packed bf16 in 32 VGPRs, probs streamed in epilogue.
//  5) k_gemm_o     : out = AO @ Wo + bo (fp32)

typedef float  f32x4  __attribute__((ext_vector_type(4)));
typedef short  s16x8  __attribute__((ext_vector_type(8)));

__device__ __forceinline__ ushort f2bf(float f) {
  union { float f; uint32_t u; } v; v.f = f;
  uint32_t u = v.u;
  return (ushort)((u + 0x7FFF + ((u >> 16) & 1)) >> 16);   // RNE
}

__device__ __forceinline__ float bf2f(uint32_t u) {
  union { uint32_t u; float f; } v; v.u = u << 16;
  return v.f;
}

__device__ __forceinline__ f32x4 mfma16(s16x8 a, s16x8 b, f32x4 c) {
  return __builtin_amdgcn_mfma_f32_16x16x32_bf16(a, b, c, 0, 0, 0);
}

// async global->LDS, 16B per lane; LDS dest wave-uniform base + lane*16
__device__ __forceinline__ void gl_lds16(const void* g, void* l) {
  typedef __attribute__((address_space(1))) const void gvoid;
  typedef __attribute__((address_space(3))) void lvoid;
  __builtin_amdgcn_global_load_lds((gvoid*)(uintptr_t)g,
                                   (lvoid*)(uint32_t)(uintptr_t)l, 16, 0, 0);
}

// ---------------------------------------------------------------- convert W
__global__ __launch_bounds__(256) void k_convert_w(
    const float* __restrict__ Wq, const float* __restrict__ Wk,
    const float* __restrict__ Wv, const float* __restrict__ Wo,
    ushort* __restrict__ WT, ushort* __restrict__ WoT) {
  int idx = blockIdx.x * 256 + threadIdx.x;  // 2048*512 total
  int row = idx >> 9;
  int k = idx & 511;
  if (row < 1536) {
    const float* W = (row < 512) ? Wq : (row < 1024 ? Wk : Wv);
    int n = row & 511;
    WT[row * 512 + k] = f2bf(W[k * 512 + n]);
  } else {
    int n = row - 1536;
    WoT[n * 512 + k] = f2bf(Wo[k * 512 + n]);
  }
}

// ---------------------------------------------------------------- QKV GEMM
__global__ __launch_bounds__(256) void k_gemm_qkv(
    const float* __restrict__ Aq, const float* __restrict__ Ak,
    const float* __restrict__ Av, const ushort* __restrict__ WT,
    const float* __restrict__ bq, const float* __restrict__ bk,
    const float* __restrict__ bv, ushort* __restrict__ Y) {
  __shared__ ushort As[128 * 64];
  __shared__ ushort Bs[128 * 64];
  const int id = blockIdx.x;                // 768
  const int xcd = id & 7, slot = id >> 3;   // slot 0..95
  const int mb = xcd * 8 + slot / 12;       // A-panel L2-local per XCD
  const int nb = slot % 12;
  const int mat = nb >> 2;
  const float* A    = (mat == 0) ? Aq : (mat == 1 ? Ak : Av);
  const float* bias = (mat == 0) ? bq : (mat == 1 ? bk : bv);
  const int tid = threadIdx.x;
  const int w = tid >> 6, l = tid & 63;
  const int wr = (w >> 1) * 64, wc = (w & 1) * 64;
  const int lr = l & 15, lg = l >> 4;
  const int srow = l >> 3, sslot = (l & 7) ^ srow;

  f32x4 acc[4][4];
#pragma unroll
  for (int i = 0; i < 4; i++)
#pragma unroll
    for (int j = 0; j < 4; j++) acc[i][j] = (f32x4){0.f, 0.f, 0.f, 0.f};

  for (int kk = 0; kk < 8; kk++) {
    const int k0 = kk * 64;
    // stage A (fused fp32->bf16)
#pragma unroll
    for (int it = 0; it < 8; it++) {
      int s2 = it * 256 + tid;             // 2048 float4 slots
      int row = s2 >> 4;
      int k4 = (s2 & 15) * 4;
      float4 v = *reinterpret_cast<const float4*>(
          &A[(size_t)(mb * 128 + row) * 512 + k0 + k4]);
      uint64_t p = (uint64_t)f2bf(v.x) | ((uint64_t)f2bf(v.y) << 16) |
                   ((uint64_t)f2bf(v.z) << 32) | ((uint64_t)f2bf(v.w) << 48);
      int boff = row * 128 + ((k4 * 2) ^ ((row & 7) << 4));
      *reinterpret_cast<uint64_t*>((char*)As + boff) = p;
    }
    // stage B via async LDS
#pragma unroll
    for (int it = 0; it < 4; it++) {
      int g8 = it * 4 + w;
      int row = g8 * 8 + srow;
      gl_lds16(&WT[(size_t)(nb * 128 + row) * 512 + k0 + sslot * 8], &Bs[g8 * 512]);
    }
    __syncthreads();
#pragma unroll
    for (int ks = 0; ks < 2; ks++) {
      s16x8 af[4], bfr[4];
#pragma unroll
      for (int mt = 0; mt < 4; mt++) {
        int row = wr + mt * 16 + lr;
        af[mt] = *reinterpret_cast<const s16x8*>(
            (char*)As + row * 128 + ((ks * 64 + lg * 16) ^ ((row & 7) << 4)));
      }
#pragma unroll
      for (int nt = 0; nt < 4; nt++) {
        int row = wc + nt * 16 + lr;
        bfr[nt] = *reinterpret_cast<const s16x8*>(
            (char*)Bs + row * 128 + ((ks * 64 + lg * 16) ^ ((row & 7) << 4)));
      }
#pragma unroll
      for (int mt = 0; mt < 4; mt++)
#pragma unroll
        for (int nt = 0; nt < 4; nt++)
          acc[mt][nt] = mfma16(af[mt], bfr[nt], acc[mt][nt]);
    }
    __syncthreads();
  }
  const int ncb = nb * 128;
#pragma unroll
  for (int nt = 0; nt < 4; nt++) {
    int gcol = ncb + wc + nt * 16 + lr;
    float bv_ = bias[gcol & 511];
#pragma unroll
    for (int mt = 0; mt < 4; mt++) {
#pragma unroll
      for (int r = 0; r < 4; r++) {
        int grow = mb * 128 + wr + mt * 16 + lg * 4 + r;
        Y[(size_t)grow * 1536 + gcol] = f2bf(acc[mt][nt][r] + bv_);
      }
    }
  }
}

// ---------------------------------------------------------------- V transpose
__global__ __launch_bounds__(256) void k_transpose_v(
    const ushort* __restrict__ Y, ushort* __restrict__ vT) {
  __shared__ ushort T[64 * 64];
  const int sc = blockIdx.x;  // 16
  const int bh = blockIdx.y;  // 64
  const int b = bh >> 3, h = bh & 7;
  const int s0 = sc * 64;
  const int tid = threadIdx.x;
#pragma unroll
  for (int it = 0; it < 2; it++) {
    int slot = it * 256 + tid;
    int srw = slot >> 3;
    int i16 = (slot & 7) * 16;
    int4 v = *reinterpret_cast<const int4*>(
        &Y[(size_t)(b * 1024 + s0 + srw) * 1536 + 1024 + h * 64 + (slot & 7) * 8]);
    *reinterpret_cast<int4*>((char*)T + srw * 128 + (i16 ^ ((srw & 7) << 4))) = v;
  }
  __syncthreads();
  const int d = tid >> 2;
  const int sseg = (tid & 3) * 16;
  int pk[8];
#pragma unroll
  for (int j = 0; j < 8; j++) {
    int s0l = sseg + 2 * j;
    uint32_t a = *reinterpret_cast<const ushort*>(
        (char*)T + s0l * 128 + ((d * 2) ^ ((s0l & 7) << 4)));
    uint32_t bb = *reinterpret_cast<const ushort*>(
        (char*)T + (s0l + 1) * 128 + ((d * 2) ^ (((s0l + 1) & 7) << 4)));
    pk[j] = (int)(a | (bb << 16));
  }
  ushort* dst = &vT[(size_t)(bh * 64 + d) * 1024 + s0 + sseg];
  int4 o0 = {pk[0], pk[1], pk[2], pk[3]};
  int4 o1 = {pk[4], pk[5], pk[6], pk[7]};
  *reinterpret_cast<int4*>(dst) = o0;
  *reinterpret_cast<int4*>(dst + 8) = o1;
}

// ---------------------------------------------------------------- attention
// Block = (b,h,16 t-rows), 4 waves (wave w owns s-cols / d-cols w*16..+15).
// Single fused pass: QK MFMA -> ee=exp(v-12) (packed bf16 in regs) -> PV MFMA
// on unnormalized P; normalize at end. All staging via global_load_lds.
__global__ __launch_bounds__(256, 4) void k_attention(
    const ushort* __restrict__ Y, const ushort* __restrict__ vT,
    const int* __restrict__ seq, const unsigned char* __restrict__ mask,
    float* __restrict__ probs, ushort* __restrict__ AO) {
  __shared__ ushort Kb[2][4096];    // 16 KB (K chunk dbuf)
  __shared__ ushort Vb[2][4096];    // 16 KB (V chunk dbuf)
  __shared__ ushort Qb[1024];       // 2 KB
  __shared__ ushort Pb[16 * 72];    // 2.25 KB bf16 P bounce
  __shared__ ushort seqm[1024];     // 2 KB (seq | mask<<8)
  __shared__ float rinv_s[16];
  float* Rbuf = reinterpret_cast<float*>(&Kb[0][0]);  // 4 KB, aliased (safe)

  const int id = blockIdx.x;              // 4096
  const int xcd = id & 7, slot = id >> 3; // 512
  const int bh = xcd * 8 + (slot >> 6);   // K/V L2-resident per XCD
  const int tb = slot & 63;
  const int b = bh >> 3, h = bh & 7;
  const int tid = threadIdx.x;
  const int w = tid >> 6, l = tid & 63;
  const int lr = l & 15, lg = l >> 4;
  const int sc_ = w * 16;
  const int srw = sc_ + lr;               // chunk-local s (QK) / d (PV)
  const int srow = l >> 3, sslot = (l & 7) ^ srow;

#pragma unroll
  for (int it = 0; it < 4; it++) {
    int s = it * 256 + tid;
    seqm[s] = (ushort)(seq[b * 1024 + s] | (mask[b * 1024 + s] ? 0x100 : 0));
  }
  // prologue staging: K0, V0, Q
#pragma unroll
  for (int it = 0; it < 2; it++) {
    int g8 = it * 4 + w;
    int row = g8 * 8 + srow;
    gl_lds16(&Y[(size_t)(b * 1024 + row) * 1536 + 512 + h * 64 + sslot * 8],
             &Kb[0][g8 * 512]);
    gl_lds16(&vT[(size_t)(bh * 64 + row) * 1024 + sslot * 8], &Vb[0][g8 * 512]);
  }
  if (w < 2) {
    gl_lds16(&Y[(size_t)(b * 1024 + tb * 16 + w * 8 + srow) * 1536 + h * 64 +
                sslot * 8],
             &Qb[w * 512]);
  }
  __syncthreads();   // seqm + K0/V0/Q ready (vmcnt drained)

  s16x8 qf0 = *reinterpret_cast<const s16x8*>(
      (char*)Qb + lr * 128 + ((lg * 16) ^ ((lr & 7) << 4)));
  s16x8 qf1 = *reinterpret_cast<const s16x8*>(
      (char*)Qb + lr * 128 + ((64 + lg * 16) ^ ((lr & 7) << 4)));
  int seqt[4];
#pragma unroll
  for (int r = 0; r < 4; r++) seqt[r] = seqm[tb * 16 + lg * 4 + r] & 255;

  uint2 pe[16];                // packed bf16 e-values: 32 VGPRs
  float psum[4] = {0.f, 0.f, 0.f, 0.f};
  f32x4 oacc = (f32x4){0.f, 0.f, 0.f, 0.f};

#pragma unroll
  for (int c = 0; c < 16; c++) {
    // prefetch next chunk (drained by this iteration's first barrier)
    if (c < 15) {
#pragma unroll
      for (int it = 0; it < 2; it++) {
        int g8 = it * 4 + w;
        int row = g8 * 8 + srow;
        gl_lds16(&Y[(size_t)(b * 1024 + (c + 1) * 64 + row) * 1536 + 512 +
                    h * 64 + sslot * 8],
                 &Kb[(c + 1) & 1][g8 * 512]);
        gl_lds16(&vT[(size_t)(bh * 64 + row) * 1024 + (c + 1) * 64 + sslot * 8],
                 &Vb[(c + 1) & 1][g8 * 512]);
      }
    }
    // QK^T for this wave's 16 s-cols
    s16x8 kf0 = *reinterpret_cast<const s16x8*>(
        (char*)&Kb[c & 1][0] + srw * 128 + ((lg * 16) ^ ((srw & 7) << 4)));
    s16x8 kf1 = *reinterpret_cast<const s16x8*>(
        (char*)&Kb[c & 1][0] + srw * 128 + ((64 + lg * 16) ^ ((srw & 7) << 4)));
    f32x4 facc = (f32x4){0.f, 0.f, 0.f, 0.f};
    facc = mfma16(qf0, kf0, facc);
    facc = mfma16(qf1, kf1, facc);

    const int sg = c * 64 + srw;
    const int sm = seqm[sg];
    const int ss = sm & 255;
    const bool msk = (sm & 0x100) != 0;
    ushort eb[4];
#pragma unroll
    for (int r = 0; r < 4; r++) {
      int tg = tb * 16 + lg * 4 + r;
      int dsep = tg - sg; dsep = dsep < 0 ? -dsep : dsep;
      int dnt = seqt[r] - ss; dnt = dnt < 0 ? -dnt : dnt;
      bool bon = (dnt == 1 && seqt[r] <= 3 && ss <= 3 && dsep >= 3);
      float v = facc[r] * 0.125f + (bon ? 2.0f : 0.0f);
      float ee = msk ? 0.0f : __expf(v - 12.0f);
      psum[r] += ee;
      eb[r] = f2bf(ee);
      Pb[(lg * 4 + r) * 72 + srw] = eb[r];
    }
    pe[c].x = (uint32_t)eb[0] | ((uint32_t)eb[1] << 16);
    pe[c].y = (uint32_t)eb[2] | ((uint32_t)eb[3] << 16);
    __syncthreads();   // Pb visible; prefetch (c+1) drained

    // PV MFMA (unnormalized): wave computes t(16) x d(16) at d-cols sc_
#pragma unroll
    for (int ks = 0; ks < 2; ks++) {
      s16x8 paf = *reinterpret_cast<const s16x8*>(&Pb[lr * 72 + ks * 32 + lg * 8]);
      s16x8 vb = *reinterpret_cast<const s16x8*>(
          (char*)&Vb[c & 1][0] + srw * 128 +
          ((ks * 64 + lg * 16) ^ ((srw & 7) << 4)));
      oacc = mfma16(paf, vb, oacc);
    }
    __syncthreads();   // Pb/V reads done before next publish/overwrite
  }

  // ---- row-sum reduce across waves/lanes (Rbuf aliases Kb: all reads done)
#pragma unroll
  for (int r = 0; r < 4; r++) Rbuf[((w * 4 + lg) * 4 + r) * 16 + lr] = psum[r];
  __syncthreads();
  {
    int row = tid >> 4, j = tid & 15;
    int lgr = row >> 2, rr = row & 3;
    float s = 0.f;
#pragma unroll
    for (int i = 0; i < 4; i++) {
      int wj = j >> 2;
      int lrj = (j & 3) * 4 + i;
      s += Rbuf[((wj * 4 + lgr) * 4 + rr) * 16 + lrj];
    }
#pragma unroll
    for (int off = 1; off < 16; off <<= 1) s += __shfl_xor(s, off);
    if (j == 0) rinv_s[row] = 1.0f / s;
  }
  __syncthreads();
  float rv[4];
#pragma unroll
  for (int r = 0; r < 4; r++) rv[r] = rinv_s[lg * 4 + r];

  // AO write (normalized)
#pragma unroll
  for (int r = 0; r < 4; r++) {
    int t = tb * 16 + lg * 4 + r;
    AO[((size_t)b * 1024 + t) * 512 + h * 64 + sc_ + lr] = f2bf(oacc[r] * rv[r]);
  }

  // ---- probs epilogue: stream from pe regs (no LDS, no barriers)
#pragma unroll
  for (int r = 0; r < 4; r++) {
    float* prow = &probs[((size_t)bh * 1024 + tb * 16 + lg * 4 + r) * 1024 + srw];
#pragma unroll
    for (int c = 0; c < 16; c++) {
      uint32_t u = (r < 2) ? pe[c].x : pe[c].y;
      u = (u >> ((r & 1) * 16)) & 0xffffu;
      prow[c * 64] = bf2f(u) * rv[r];
    }
  }
}

// ---------------------------------------------------------------- out GEMM
__global__ __launch_bounds__(256) void k_gemm_o(
    const ushort* __restrict__ AO, const ushort* __restrict__ WoT,
    const float* __restrict__ bo, float* __restrict__ out) {
  __shared__ ushort As[128 * 64];
  __shared__ ushort Bs[128 * 64];
  const int id = blockIdx.x;               // 256
  const int xcd = id & 7, slot = id >> 3;  // 0..31
  const int mb = xcd * 8 + (slot >> 2);
  const int nb = slot & 3;
  const int tid = threadIdx.x;
  const int w = tid >> 6, l = tid & 63;
  const int wr = (w >> 1) * 64, wc = (w & 1) * 64;
  const int lr = l & 15, lg = l >> 4;
  const int srow = l >> 3, sslot = (l & 7) ^ srow;

  f32x4 acc[4][4];
#pragma unroll
  for (int i = 0; i < 4; i++)
#pragma unroll
    for (int j = 0; j < 4; j++) acc[i][j] = (f32x4){0.f, 0.f, 0.f, 0.f};

  for (int kk = 0; kk < 8; kk++) {
    const int k0 = kk * 64;
#pragma unroll
    for (int it = 0; it < 4; it++) {
      int g8 = it * 4 + w;
      int row = g8 * 8 + srow;
      gl_lds16(&AO[(size_t)(mb * 128 + row) * 512 + k0 + sslot * 8], &As[g8 * 512]);
      gl_lds16(&WoT[(size_t)(nb * 128 + row) * 512 + k0 + sslot * 8], &Bs[g8 * 512]);
    }
    __syncthreads();
#pragma unroll
    for (int ks = 0; ks < 2; ks++) {
      s16x8 af[4], bfr[4];
#pragma unroll
      for (int mt = 0; mt < 4; mt++) {
        int row = wr + mt * 16 + lr;
        af[mt] = *reinterpret_cast<const s16x8*>(
            (char*)As + row * 128 + ((ks * 64 + lg * 16) ^ ((row & 7) << 4)));
      }
#pragma unroll
      for (int nt = 0; nt < 4; nt++) {
        int row = wc + nt * 16 + lr;
        bfr[nt] = *reinterpret_cast<const s16x8*>(
            (char*)Bs + row * 128 + ((ks * 64 + lg * 16) ^ ((row & 7) << 4)));
      }
#pragma unroll
      for (int mt = 0; mt < 4; mt++)
#pragma unroll
        for (int nt = 0; nt < 4; nt++)
          acc[mt][nt] = mfma16(af[mt], bfr[nt], acc[mt][nt]);
    }
    __syncthreads();
  }
  const int ncb = nb * 128;
#pragma unroll
  for (int nt = 0; nt < 4; nt++) {
    int gcol = ncb + wc + nt * 16 + lr;
    float bv_ = bo[gcol];
#pragma unroll
    for (int mt = 0; mt < 4; mt++) {
#pragma unroll
      for (int r = 0; r < 4; r++) {
        int grow = mb * 128 + wr + mt * 16 + lg * 4 + r;
        out[(size_t)grow * 512 + gcol] = acc[mt][nt][r] + bv_;
      }
    }
  }
}

// ---------------------------------------------------------------- launch
extern "C" void kernel_launch(void* const* d_in, const int* in_sizes, int n_in,
                              void* d_out, int out_size, void* d_ws, size_t ws_size,
                              hipStream_t stream) {
  (void)in_sizes; (void)n_in; (void)out_size; (void)ws_size;
  const float* query = (const float*)d_in[0];
  const float* key   = (const float*)d_in[1];
  const float* value = (const float*)d_in[2];
  const int* seq     = (const int*)d_in[3];
  const unsigned char* mask = (const unsigned char*)d_in[4];
  const float* Wq = (const float*)d_in[5];
  const float* bq = (const float*)d_in[6];
  const float* Wk = (const float*)d_in[7];
  const float* bk = (const float*)d_in[8];
  const float* Wv = (const float*)d_in[9];
  const float* bv = (const float*)d_in[10];
  const float* Wo = (const float*)d_in[11];
  const float* bo = (const float*)d_in[12];

  float* out = (float*)d_out;
  float* probs = out + (size_t)8 * 1024 * 512;

  char* ws = (char*)d_ws;
  ushort* Y   = (ushort*)(ws);               // 25,165,824 B
  ushort* WT  = (ushort*)(ws + 25165824);    // 1,572,864 B
  ushort* WoT = (ushort*)(ws + 26738688);    //   524,288 B
  ushort* vT  = (ushort*)(ws + 27262976);    // 8,388,608 B
  ushort* AO  = (ushort*)(ws + 35651584);    // 8,388,608 B (total 44,040,192)

  k_convert_w<<<4096, 256, 0, stream>>>(Wq, Wk, Wv, Wo, WT, WoT);
  k_gemm_qkv<<<768, 256, 0, stream>>>(query, key, value, WT, bq, bk, bv, Y);
  k_transpose_v<<<dim3(16, 64), 256, 0, stream>>>(Y, vT);
  k_attention<<<4096, 256, 0, stream>>>(Y, vT, seq, mask, probs, AO);
  k_gemm_o<<<256, 256, 0, stream>>>(AO, WoT, bo, out);
}

// Round 6
// 217.138 us; speedup vs baseline: 1.2666x; 1.0113x over previous
//
#include <hip/hip_runtime.h>
#include <hip/hip_bf16.h>
#include <stdint.h>

// BasePairingAttention: B=8, S=T=1024, E=512, H=8, D=64
// Pipeline (5 kernels):
//  1) k_convert_w  : Wq/Wk/Wv/Wo fp32 -> transposed bf16 (WT[n][k], WoT)
//  2) k_gemm_qkv   : Y[8192][1536] = [q|k|v] @ W^T + bias (bf16)
//  3) k_transpose_v: vT[(b*8+h)*64+d][s] bf16
//  4) k_attention  : single fused pass; K/V staged wave-private via
//                    global_load_lds with COUNTED vmcnt (never drained to 0
//                    in the loop, T3/T4); raw s_barrier+lgkmcnt for the Pb
//                    bounce; probs written via LDS bounce as float4 runs.
//  5) k_gemm_o     : out = AO @ Wo + bo (fp32)

typedef float  f32x4  __attribute__((ext_vector_type(4)));
typedef short  s16x8  __attribute__((ext_vector_type(8)));

__device__ __forceinline__ ushort f2bf(float f) {
  union { float f; uint32_t u; } v; v.f = f;
  uint32_t u = v.u;
  return (ushort)((u + 0x7FFF + ((u >> 16) & 1)) >> 16);   // RNE
}

__device__ __forceinline__ float bf2f(uint32_t u) {
  union { uint32_t u; float f; } v; v.u = u << 16;
  return v.f;
}

__device__ __forceinline__ f32x4 mfma16(s16x8 a, s16x8 b, f32x4 c) {
  return __builtin_amdgcn_mfma_f32_16x16x32_bf16(a, b, c, 0, 0, 0);
}

// async global->LDS, 16B per lane; LDS dest wave-uniform base + lane*16
__device__ __forceinline__ void gl_lds16(const void* g, void* l) {
  typedef __attribute__((address_space(1))) const void gvoid;
  typedef __attribute__((address_space(3))) void lvoid;
  __builtin_amdgcn_global_load_lds((gvoid*)(uintptr_t)g,
                                   (lvoid*)(uint32_t)(uintptr_t)l, 16, 0, 0);
}

// counted vmem waits (T4): never drain to 0 inside the loop
__device__ __forceinline__ void vwait4() {
  asm volatile("s_waitcnt vmcnt(4)" ::: "memory");
  __builtin_amdgcn_sched_barrier(0);
}
__device__ __forceinline__ void vwait0() {
  asm volatile("s_waitcnt vmcnt(0)" ::: "memory");
  __builtin_amdgcn_sched_barrier(0);
}
// LDS-only barrier: ds-writes visible, vmem stays in flight
__device__ __forceinline__ void bar_lds() {
  asm volatile("s_waitcnt lgkmcnt(0)" ::: "memory");
  __builtin_amdgcn_s_barrier();
  __builtin_amdgcn_sched_barrier(0);
}

// ---------------------------------------------------------------- convert W
__global__ __launch_bounds__(256) void k_convert_w(
    const float* __restrict__ Wq, const float* __restrict__ Wk,
    const float* __restrict__ Wv, const float* __restrict__ Wo,
    ushort* __restrict__ WT, ushort* __restrict__ WoT) {
  int idx = blockIdx.x * 256 + threadIdx.x;  // 2048*512 total
  int row = idx >> 9;
  int k = idx & 511;
  if (row < 1536) {
    const float* W = (row < 512) ? Wq : (row < 1024 ? Wk : Wv);
    int n = row & 511;
    WT[row * 512 + k] = f2bf(W[k * 512 + n]);
  } else {
    int n = row - 1536;
    WoT[n * 512 + k] = f2bf(Wo[k * 512 + n]);
  }
}

// ---------------------------------------------------------------- QKV GEMM
__global__ __launch_bounds__(256) void k_gemm_qkv(
    const float* __restrict__ Aq, const float* __restrict__ Ak,
    const float* __restrict__ Av, const ushort* __restrict__ WT,
    const float* __restrict__ bq, const float* __restrict__ bk,
    const float* __restrict__ bv, ushort* __restrict__ Y) {
  __shared__ ushort As[128 * 64];
  __shared__ ushort Bs[128 * 64];
  const int id = blockIdx.x;                // 768
  const int xcd = id & 7, slot = id >> 3;   // slot 0..95
  const int mb = xcd * 8 + slot / 12;       // A-panel L2-local per XCD
  const int nb = slot % 12;
  const int mat = nb >> 2;
  const float* A    = (mat == 0) ? Aq : (mat == 1 ? Ak : Av);
  const float* bias = (mat == 0) ? bq : (mat == 1 ? bk : bv);
  const int tid = threadIdx.x;
  const int w = tid >> 6, l = tid & 63;
  const int wr = (w >> 1) * 64, wc = (w & 1) * 64;
  const int lr = l & 15, lg = l >> 4;
  const int srow = l >> 3, sslot = (l & 7) ^ srow;

  f32x4 acc[4][4];
#pragma unroll
  for (int i = 0; i < 4; i++)
#pragma unroll
    for (int j = 0; j < 4; j++) acc[i][j] = (f32x4){0.f, 0.f, 0.f, 0.f};

  for (int kk = 0; kk < 8; kk++) {
    const int k0 = kk * 64;
    // stage A (fused fp32->bf16)
#pragma unroll
    for (int it = 0; it < 8; it++) {
      int s2 = it * 256 + tid;             // 2048 float4 slots
      int row = s2 >> 4;
      int k4 = (s2 & 15) * 4;
      float4 v = *reinterpret_cast<const float4*>(
          &A[(size_t)(mb * 128 + row) * 512 + k0 + k4]);
      uint64_t p = (uint64_t)f2bf(v.x) | ((uint64_t)f2bf(v.y) << 16) |
                   ((uint64_t)f2bf(v.z) << 32) | ((uint64_t)f2bf(v.w) << 48);
      int boff = row * 128 + ((k4 * 2) ^ ((row & 7) << 4));
      *reinterpret_cast<uint64_t*>((char*)As + boff) = p;
    }
    // stage B via async LDS
#pragma unroll
    for (int it = 0; it < 4; it++) {
      int g8 = it * 4 + w;
      int row = g8 * 8 + srow;
      gl_lds16(&WT[(size_t)(nb * 128 + row) * 512 + k0 + sslot * 8], &Bs[g8 * 512]);
    }
    __syncthreads();
#pragma unroll
    for (int ks = 0; ks < 2; ks++) {
      s16x8 af[4], bfr[4];
#pragma unroll
      for (int mt = 0; mt < 4; mt++) {
        int row = wr + mt * 16 + lr;
        af[mt] = *reinterpret_cast<const s16x8*>(
            (char*)As + row * 128 + ((ks * 64 + lg * 16) ^ ((row & 7) << 4)));
      }
#pragma unroll
      for (int nt = 0; nt < 4; nt++) {
        int row = wc + nt * 16 + lr;
        bfr[nt] = *reinterpret_cast<const s16x8*>(
            (char*)Bs + row * 128 + ((ks * 64 + lg * 16) ^ ((row & 7) << 4)));
      }
#pragma unroll
      for (int mt = 0; mt < 4; mt++)
#pragma unroll
        for (int nt = 0; nt < 4; nt++)
          acc[mt][nt] = mfma16(af[mt], bfr[nt], acc[mt][nt]);
    }
    __syncthreads();
  }
  const int ncb = nb * 128;
#pragma unroll
  for (int nt = 0; nt < 4; nt++) {
    int gcol = ncb + wc + nt * 16 + lr;
    float bv_ = bias[gcol & 511];
#pragma unroll
    for (int mt = 0; mt < 4; mt++) {
#pragma unroll
      for (int r = 0; r < 4; r++) {
        int grow = mb * 128 + wr + mt * 16 + lg * 4 + r;
        Y[(size_t)grow * 1536 + gcol] = f2bf(acc[mt][nt][r] + bv_);
      }
    }
  }
}

// ---------------------------------------------------------------- V transpose
__global__ __launch_bounds__(256) void k_transpose_v(
    const ushort* __restrict__ Y, ushort* __restrict__ vT) {
  __shared__ ushort T[64 * 64];
  const int sc = blockIdx.x;  // 16
  const int bh = blockIdx.y;  // 64
  const int b = bh >> 3, h = bh & 7;
  const int s0 = sc * 64;
  const int tid = threadIdx.x;
#pragma unroll
  for (int it = 0; it < 2; it++) {
    int slot = it * 256 + tid;
    int srw = slot >> 3;
    int i16 = (slot & 7) * 16;
    int4 v = *reinterpret_cast<const int4*>(
        &Y[(size_t)(b * 1024 + s0 + srw) * 1536 + 1024 + h * 64 + (slot & 7) * 8]);
    *reinterpret_cast<int4*>((char*)T + srw * 128 + (i16 ^ ((srw & 7) << 4))) = v;
  }
  __syncthreads();
  const int d = tid >> 2;
  const int sseg = (tid & 3) * 16;
  int pk[8];
#pragma unroll
  for (int j = 0; j < 8; j++) {
    int s0l = sseg + 2 * j;
    uint32_t a = *reinterpret_cast<const ushort*>(
        (char*)T + s0l * 128 + ((d * 2) ^ ((s0l & 7) << 4)));
    uint32_t bb = *reinterpret_cast<const ushort*>(
        (char*)T + (s0l + 1) * 128 + ((d * 2) ^ (((s0l + 1) & 7) << 4)));
    pk[j] = (int)(a | (bb << 16));
  }
  ushort* dst = &vT[(size_t)(bh * 64 + d) * 1024 + s0 + sseg];
  int4 o0 = {pk[0], pk[1], pk[2], pk[3]};
  int4 o1 = {pk[4], pk[5], pk[6], pk[7]};
  *reinterpret_cast<int4*>(dst) = o0;
  *reinterpret_cast<int4*>(dst + 8) = o1;
}

// ---------------------------------------------------------------- attention
// Block = (b,h,16 t-rows), 4 waves (wave w owns s-cols / d-cols w*16..+15).
// Wave-private K/V staging: wave w loads ONLY rows [w*16, w*16+16) of each
// chunk (the rows it reads) -> its own vmcnt covers its LDS data, so a
// counted vmcnt(4) + raw s_barrier keeps next-chunk loads in flight across
// the whole iteration. Pb (cross-wave) guarded by lgkmcnt(0)+s_barrier.
__global__ __launch_bounds__(256, 4) void k_attention(
    const ushort* __restrict__ Y, const ushort* __restrict__ vT,
    const int* __restrict__ seq, const unsigned char* __restrict__ mask,
    float* __restrict__ probs, ushort* __restrict__ AO) {
  __shared__ ushort Kb[2][4096];    // 16 KB (K chunk dbuf)
  __shared__ ushort Vb[2][4096];    // 16 KB (V chunk dbuf)
  __shared__ ushort Qb[1024];       // 2 KB
  __shared__ ushort Pb[16 * 72];    // 2.25 KB bf16 P bounce
  __shared__ ushort seqm[1024];     // 2 KB (seq | mask<<8)
  __shared__ float rinv_s[16];
  float* Rbuf = reinterpret_cast<float*>(&Kb[0][0]);  // 4 KB alias (guarded)

  const int id = blockIdx.x;              // 4096
  const int xcd = id & 7, slot = id >> 3; // 512
  const int bh = xcd * 8 + (slot >> 6);   // K/V L2-resident per XCD
  const int tb = slot & 63;
  const int b = bh >> 3, h = bh & 7;
  const int tid = threadIdx.x;
  const int w = tid >> 6, l = tid & 63;
  const int lr = l & 15, lg = l >> 4;
  const int sc_ = w * 16;
  const int srw = sc_ + lr;               // chunk-local s (QK) / d (PV)
  const int srow = l >> 3, sslot = (l & 7) ^ srow;

#pragma unroll
  for (int it = 0; it < 4; it++) {
    int s = it * 256 + tid;
    seqm[s] = (ushort)(seq[b * 1024 + s] | (mask[b * 1024 + s] ? 0x100 : 0));
  }
  // prologue staging: K0, V0 (wave-private rows), Q
#pragma unroll
  for (int it = 0; it < 2; it++) {
    int g8 = w * 2 + it;                  // wave w owns groups {2w, 2w+1}
    int row = g8 * 8 + srow;              // rows w*16 .. w*16+15
    gl_lds16(&Y[(size_t)(b * 1024 + row) * 1536 + 512 + h * 64 + sslot * 8],
             &Kb[0][g8 * 512]);
    gl_lds16(&vT[(size_t)(bh * 64 + row) * 1024 + sslot * 8], &Vb[0][g8 * 512]);
  }
  if (w < 2) {
    gl_lds16(&Y[(size_t)(b * 1024 + tb * 16 + w * 8 + srow) * 1536 + h * 64 +
                sslot * 8],
             &Qb[w * 512]);
  }
  __syncthreads();   // prologue: full drain once (seqm + K0/V0/Q ready)

  s16x8 qf0 = *reinterpret_cast<const s16x8*>(
      (char*)Qb + lr * 128 + ((lg * 16) ^ ((lr & 7) << 4)));
  s16x8 qf1 = *reinterpret_cast<const s16x8*>(
      (char*)Qb + lr * 128 + ((64 + lg * 16) ^ ((lr & 7) << 4)));
  int seqt[4];
#pragma unroll
  for (int r = 0; r < 4; r++) seqt[r] = seqm[tb * 16 + lg * 4 + r] & 255;

  uint2 pe[16];                // packed bf16 e-values: 32 VGPRs
  float psum[4] = {0.f, 0.f, 0.f, 0.f};
  f32x4 oacc = (f32x4){0.f, 0.f, 0.f, 0.f};

#pragma unroll
  for (int c = 0; c < 16; c++) {
    // prefetch next chunk (wave-private rows), keep in flight across iter
    if (c < 15) {
#pragma unroll
      for (int it = 0; it < 2; it++) {
        int g8 = w * 2 + it;
        int row = g8 * 8 + srow;
        gl_lds16(&Y[(size_t)(b * 1024 + (c + 1) * 64 + row) * 1536 + 512 +
                    h * 64 + sslot * 8],
                 &Kb[(c + 1) & 1][g8 * 512]);
        gl_lds16(&vT[(size_t)(bh * 64 + row) * 1024 + (c + 1) * 64 + sslot * 8],
                 &Vb[(c + 1) & 1][g8 * 512]);
      }
      vwait4();   // chunk c's 4 loads done; c+1's 4 stay outstanding
    } else {
      vwait0();   // last chunk: drain
    }
    // QK^T for this wave's 16 s-cols (self-staged rows)
    s16x8 kf0 = *reinterpret_cast<const s16x8*>(
        (char*)&Kb[c & 1][0] + srw * 128 + ((lg * 16) ^ ((srw & 7) << 4)));
    s16x8 kf1 = *reinterpret_cast<const s16x8*>(
        (char*)&Kb[c & 1][0] + srw * 128 + ((64 + lg * 16) ^ ((srw & 7) << 4)));
    f32x4 facc = (f32x4){0.f, 0.f, 0.f, 0.f};
    facc = mfma16(qf0, kf0, facc);
    facc = mfma16(qf1, kf1, facc);

    const int sg = c * 64 + srw;
    const int sm = seqm[sg];
    const int ss = sm & 255;
    const bool msk = (sm & 0x100) != 0;
    ushort eb[4];
#pragma unroll
    for (int r = 0; r < 4; r++) {
      int tg = tb * 16 + lg * 4 + r;
      int dsep = tg - sg; dsep = dsep < 0 ? -dsep : dsep;
      int dnt = seqt[r] - ss; dnt = dnt < 0 ? -dnt : dnt;
      bool bon = (dnt == 1 && seqt[r] <= 3 && ss <= 3 && dsep >= 3);
      float v = facc[r] * 0.125f + (bon ? 2.0f : 0.0f);
      float ee = msk ? 0.0f : __expf(v - 12.0f);
      psum[r] += ee;
      eb[r] = f2bf(ee);
      Pb[(lg * 4 + r) * 72 + srw] = eb[r];
    }
    pe[c].x = (uint32_t)eb[0] | ((uint32_t)eb[1] << 16);
    pe[c].y = (uint32_t)eb[2] | ((uint32_t)eb[3] << 16);
    bar_lds();   // Pb visible to all waves (vmem stays in flight)

    // PV MFMA (unnormalized): wave computes t(16) x d(16) at d-cols sc_
#pragma unroll
    for (int ks = 0; ks < 2; ks++) {
      s16x8 paf = *reinterpret_cast<const s16x8*>(&Pb[lr * 72 + ks * 32 + lg * 8]);
      s16x8 vb = *reinterpret_cast<const s16x8*>(
          (char*)&Vb[c & 1][0] + srw * 128 +
          ((ks * 64 + lg * 16) ^ ((srw & 7) << 4)));
      oacc = mfma16(paf, vb, oacc);
    }
    bar_lds();   // Pb WAR protection before next publish
  }

  // ---- row-sum reduce across waves/lanes (Rbuf aliases Kb: reads done)
#pragma unroll
  for (int r = 0; r < 4; r++) Rbuf[((w * 4 + lg) * 4 + r) * 16 + lr] = psum[r];
  __syncthreads();
  {
    int row = tid >> 4, j = tid & 15;
    int lgr = row >> 2, rr = row & 3;
    float s = 0.f;
#pragma unroll
    for (int i = 0; i < 4; i++) {
      int wj = j >> 2;
      int lrj = (j & 3) * 4 + i;
      s += Rbuf[((wj * 4 + lgr) * 4 + rr) * 16 + lrj];
    }
#pragma unroll
    for (int off = 1; off < 16; off <<= 1) s += __shfl_xor(s, off);
    if (j == 0) rinv_s[row] = 1.0f / s;
  }
  __syncthreads();
  float rv[4];
#pragma unroll
  for (int r = 0; r < 4; r++) rv[r] = rinv_s[lg * 4 + r];

  // AO write (normalized)
#pragma unroll
  for (int r = 0; r < 4; r++) {
    int t = tb * 16 + lg * 4 + r;
    AO[((size_t)b * 1024 + t) * 512 + h * 64 + sc_ + lr] = f2bf(oacc[r] * rv[r]);
  }

  // ---- probs epilogue: LDS bounce per chunk -> fully coalesced float4 runs
  float* Pf = reinterpret_cast<float*>(&Kb[0][0]);  // 16x68 f32 (4.25 KB)
  const int prow_ = tid >> 4, pj = tid & 15;
  float* pdst_base = &probs[((size_t)bh * 1024 + tb * 16 + prow_) * 1024 + pj * 4];
#pragma unroll
  for (int c = 0; c < 16; c++) {
#pragma unroll
    for (int r = 0; r < 4; r++) {
      uint32_t u = (r < 2) ? pe[c].x : pe[c].y;
      u = (u >> ((r & 1) * 16)) & 0xffffu;
      Pf[(lg * 4 + r) * 68 + srw] = bf2f(u) * rv[r];
    }
    bar_lds();   // Pf chunk visible (global store-acks stay in flight)
    float4 p4 = *reinterpret_cast<const float4*>(&Pf[prow_ * 68 + pj * 4]);
    *reinterpret_cast<float4*>(pdst_base + c * 64) = p4;
    bar_lds();   // Pf WAR before next chunk
  }
}

// ---------------------------------------------------------------- out GEMM
__global__ __launch_bounds__(256) void k_gemm_o(
    const ushort* __restrict__ AO, const ushort* __restrict__ WoT,
    const float* __restrict__ bo, float* __restrict__ out) {
  __shared__ ushort As[128 * 64];
  __shared__ ushort Bs[128 * 64];
  const int id = blockIdx.x;               // 256
  const int xcd = id & 7, slot = id >> 3;  // 0..31
  const int mb = xcd * 8 + (slot >> 2);
  const int nb = slot & 3;
  const int tid = threadIdx.x;
  const int w = tid >> 6, l = tid & 63;
  const int wr = (w >> 1) * 64, wc = (w & 1) * 64;
  const int lr = l & 15, lg = l >> 4;
  const int srow = l >> 3, sslot = (l & 7) ^ srow;

  f32x4 acc[4][4];
#pragma unroll
  for (int i = 0; i < 4; i++)
#pragma unroll
    for (int j = 0; j < 4; j++) acc[i][j] = (f32x4){0.f, 0.f, 0.f, 0.f};

  for (int kk = 0; kk < 8; kk++) {
    const int k0 = kk * 64;
#pragma unroll
    for (int it = 0; it < 4; it++) {
      int g8 = it * 4 + w;
      int row = g8 * 8 + srow;
      gl_lds16(&AO[(size_t)(mb * 128 + row) * 512 + k0 + sslot * 8], &As[g8 * 512]);
      gl_lds16(&WoT[(size_t)(nb * 128 + row) * 512 + k0 + sslot * 8], &Bs[g8 * 512]);
    }
    __syncthreads();
#pragma unroll
    for (int ks = 0; ks < 2; ks++) {
      s16x8 af[4], bfr[4];
#pragma unroll
      for (int mt = 0; mt < 4; mt++) {
        int row = wr + mt * 16 + lr;
        af[mt] = *reinterpret_cast<const s16x8*>(
            (char*)As + row * 128 + ((ks * 64 + lg * 16) ^ ((row & 7) << 4)));
      }
#pragma unroll
      for (int nt = 0; nt < 4; nt++) {
        int row = wc + nt * 16 + lr;
        bfr[nt] = *reinterpret_cast<const s16x8*>(
            (char*)Bs + row * 128 + ((ks * 64 + lg * 16) ^ ((row & 7) << 4)));
      }
#pragma unroll
      for (int mt = 0; mt < 4; mt++)
#pragma unroll
        for (int nt = 0; nt < 4; nt++)
          acc[mt][nt] = mfma16(af[mt], bfr[nt], acc[mt][nt]);
    }
    __syncthreads();
  }
  const int ncb = nb * 128;
#pragma unroll
  for (int nt = 0; nt < 4; nt++) {
    int gcol = ncb + wc + nt * 16 + lr;
    float bv_ = bo[gcol];
#pragma unroll
    for (int mt = 0; mt < 4; mt++) {
#pragma unroll
      for (int r = 0; r < 4; r++) {
        int grow = mb * 128 + wr + mt * 16 + lg * 4 + r;
        out[(size_t)grow * 512 + gcol] = acc[mt][nt][r] + bv_;
      }
    }
  }
}

// ---------------------------------------------------------------- launch
extern "C" void kernel_launch(void* const* d_in, const int* in_sizes, int n_in,
                              void* d_out, int out_size, void* d_ws, size_t ws_size,
                              hipStream_t stream) {
  (void)in_sizes; (void)n_in; (void)out_size; (void)ws_size;
  const float* query = (const float*)d_in[0];
  const float* key   = (const float*)d_in[1];
  const float* value = (const float*)d_in[2];
  const int* seq     = (const int*)d_in[3];
  const unsigned char* mask = (const unsigned char*)d_in[4];
  const float* Wq = (const float*)d_in[5];
  const float* bq = (const float*)d_in[6];
  const float* Wk = (const float*)d_in[7];
  const float* bk = (const float*)d_in[8];
  const float* Wv = (const float*)d_in[9];
  const float* bv = (const float*)d_in[10];
  const float* Wo = (const float*)d_in[11];
  const float* bo = (const float*)d_in[12];

  float* out = (float*)d_out;
  float* probs = out + (size_t)8 * 1024 * 512;

  char* ws = (char*)d_ws;
  ushort* Y   = (ushort*)(ws);               // 25,165,824 B
  ushort* WT  = (ushort*)(ws + 25165824);    // 1,572,864 B
  ushort* WoT = (ushort*)(ws + 26738688);    //   524,288 B
  ushort* vT  = (ushort*)(ws + 27262976);    // 8,388,608 B
  ushort* AO  = (ushort*)(ws + 35651584);    // 8,388,608 B (total 44,040,192)

  k_convert_w<<<4096, 256, 0, stream>>>(Wq, Wk, Wv, Wo, WT, WoT);
  k_gemm_qkv<<<768, 256, 0, stream>>>(query, key, value, WT, bq, bk, bv, Y);
  k_transpose_v<<<dim3(16, 64), 256, 0, stream>>>(Y, vT);
  k_attention<<<4096, 256, 0, stream>>>(Y, vT, seq, mask, probs, AO);
  k_gemm_o<<<256, 256, 0, stream>>>(AO, WoT, bo, out);
}